// Round 1
// 118.750 us; speedup vs baseline: 1.0249x; 1.0249x over previous
//
#include <hip/hip_runtime.h>

// ETNN layer, N=50000 cells, HID=64, DEG=16 neighbors, 4 nodes/cell, sp=3.
//
// Bilinear split of the per-pair message MLP:
//   x@W1 = f_i@W1[0:64] + f_j@W1[64:128] + geom*W1[128]
// -> prep_aux (fused, 1660 blocks):
//      blocks [0,782): prep role — feat fp32->bf16 frags in-reg,
//        Q = feat@W1bot as fp8 e4m3 (64B rows). Q-half W1 frags are
//        self-staged from raw W1 through 8KB LDS (no w1pq dependency).
//      blocks [782,1660): aux role — positions passthrough, weight
//        pre-swizzle (w1pq/w2t/wu1t/wu2b), centroids cent4.
// -> msg_tail: block = one 16-cell tile (3125 blocks, 4 waves):
//      early: b1/W1L + nbr rows + cent4 gathers + g for all 4 cells,
//             feat row -> bf16 frags (kept in regs for phase 0 AND stage 2)
//      phase 0: P-tile^T = W1top^T x X^T (MFMA) -> LDS (bf16);
//               prefetch cell0's 16 Q8 rows (readlane-addressed) pre-barrier
//      phase A: per wave 4 cells, double-buffered Q8 prefetch (qA/qB):
//               s = mean_d silu(P+Q[nbr]+g*w1L+b1) -> overwrites P rows in LDS
//      phase B: msg^T = W2^T x s^T (+b2) -> LDS; hu^T = Wu1^T x [feat|msg]^T
//               (+bu1, silu) -> LDS; out = hu x Wu2 + bu2 + feat.
//
// MFMA layouts (HW-verified): A[m=lane&15][k=quad*8+j], B[k=quad*8+j][n=lane&15],
// D[row=quad*4+reg][col=lane&15].

#define DEG 16

typedef __attribute__((ext_vector_type(8))) short short8;   // 8 bf16
typedef __attribute__((ext_vector_type(4))) float f32x4;    // MFMA acc
typedef uint2 uint2_a __attribute__((may_alias));
typedef uint4 uint4_a __attribute__((may_alias));
typedef unsigned short ushort_a __attribute__((may_alias));

union HbRd { uint4_a u; short8 s; };
union Frag { short8 s; uint4 u; };

__device__ __forceinline__ unsigned f2bf(float f) {
  unsigned u = __float_as_uint(f);
  return (u + 0x7FFFu + ((u >> 16) & 1u)) >> 16;   // RNE fp32->bf16
}
__device__ __forceinline__ float bf2f(unsigned bits16) {
  return __uint_as_float(bits16 << 16);
}
__device__ __forceinline__ float silu(float h) {
  return h / (1.f + __expf(-h));
}
__device__ __forceinline__ float silu_fast(float h) {
  return h * __builtin_amdgcn_rcpf(1.f + __expf(-h));
}

// ------------------------------------------------------------ prep_aux ----
// blocks [0,782): prep role | blocks [782,1660): aux role.
__global__ __launch_bounds__(256) void prep_aux_kernel(
    const float* __restrict__ feat,
    const float* __restrict__ pos,
    const float* __restrict__ W1, const float* __restrict__ W2,
    const float* __restrict__ Wu1, const float* __restrict__ Wu2,
    float* __restrict__ outpos, float* __restrict__ cent4,
    unsigned short* __restrict__ w1pq, unsigned short* __restrict__ w2t,
    unsigned short* __restrict__ wu1t, unsigned short* __restrict__ wu2b,
    unsigned char* __restrict__ Q8)
{
  __shared__ unsigned short w1q[4096];   // Q-half W1 frags (bf16)

  if (blockIdx.x < 782) {
    // ------------------------------- prep role -------------------------
    const int tid  = threadIdx.x;
    const int lane = tid & 63;
    const int wid  = tid >> 6;
    const int quad = lane >> 4;
    const int l15  = lane & 15;

    // stage Q-half W1 frags into LDS; layout identical to w1pq's Q half:
    // s = ((mq*2+kk)*4+q)*128 + l*8 + j, elem = W1[(64+kk*32+q*8+j)*64 + mq*16+l]
    {
      const int q  = (tid >> 3) & 3;
      const int kk = (tid >> 5) & 1;
      const int mq = tid >> 6;
      #pragma unroll
      for (int u = 0; u < 2; ++u) {
        const int l = (tid * 2 + u) & 15;
        const float* src = W1 + (64 + kk * 32 + q * 8) * 64 + mq * 16 + l;
        unsigned short v[8];
        #pragma unroll
        for (int j = 0; j < 8; ++j)
          v[j] = (unsigned short)f2bf(src[j * 64]);
        uint4 pk;
        pk.x = (unsigned)v[0] | ((unsigned)v[1] << 16);
        pk.y = (unsigned)v[2] | ((unsigned)v[3] << 16);
        pk.z = (unsigned)v[4] | ((unsigned)v[5] << 16);
        pk.w = (unsigned)v[6] | ((unsigned)v[7] << 16);
        ((uint4*)w1q)[tid * 2 + u] = pk;
      }
    }

    const int tile = blockIdx.x * 4 + wid;
    const bool act = (tile < 3125);
    const int  tt  = act ? tile : 3124;
    const int  cr  = tt * 16 + l15;

    // feat rows -> bf16 frags (B-layout), kept in regs (no featb store)
    short8 xf[2];
    #pragma unroll
    for (int kk = 0; kk < 2; ++kk) {
      const float4 f0 = *(const float4*)(feat + cr * 64 + kk * 32 + quad * 8);
      const float4 f1 = *(const float4*)(feat + cr * 64 + kk * 32 + quad * 8 + 4);
      Frag v;
      v.s[0] = (short)f2bf(f0.x); v.s[1] = (short)f2bf(f0.y);
      v.s[2] = (short)f2bf(f0.z); v.s[3] = (short)f2bf(f0.w);
      v.s[4] = (short)f2bf(f1.x); v.s[5] = (short)f2bf(f1.y);
      v.s[6] = (short)f2bf(f1.z); v.s[7] = (short)f2bf(f1.w);
      xf[kk] = v.s;
    }

    __syncthreads();

    short8 wf[4][2];
    #pragma unroll
    for (int m = 0; m < 4; ++m)
      #pragma unroll
      for (int kk = 0; kk < 2; ++kk)
        wf[m][kk] = *(const short8*)(w1q + (((m * 2 + kk) * 4 + quad) << 7) + l15 * 8);

    f32x4 acc[4] = {};
    #pragma unroll
    for (int kk = 0; kk < 2; ++kk)
      #pragma unroll
      for (int m = 0; m < 4; ++m)
        acc[m] = __builtin_amdgcn_mfma_f32_16x16x32_bf16(wf[m][kk], xf[kk], acc[m], 0, 0, 0);

    if (act) {
      #pragma unroll
      for (int m = 0; m < 4; ++m) {          // Q: fp8 e4m3 (HW cvt pair)
        int w = __builtin_amdgcn_cvt_pk_fp8_f32(acc[m][0], acc[m][1], 0, false);
        w = __builtin_amdgcn_cvt_pk_fp8_f32(acc[m][2], acc[m][3], w, true);
        *(unsigned int*)(Q8 + cr * 64 + m * 16 + quad * 4) = (unsigned)w;
      }
    }
  } else {
    // ------------------------------- aux role --------------------------
    const int t = (blockIdx.x - 782) * 256 + threadIdx.x;
    if (t < 150000) {
      ((float4*)outpos)[t] = ((const float4*)pos)[t];
    } else if (t < 174576) {
      const int r = t - 150000;
      if (r < 8192) {
        // w1pq: A-frags of [W1top|W1bot]^T, [mt 0..7][kk 0..1]
        const int j = r & 7, l = (r >> 3) & 15, q = (r >> 7) & 3;
        const int f = r >> 9, kk = f & 1, mt = f >> 1;
        const int k = kk * 32 + q * 8 + j;        // feat dim 0..63
        const int m = mt * 16 + l;                // pq col 0..127
        w1pq[r] = (unsigned short)f2bf(
            (m < 64) ? W1[k * 64 + m] : W1[(k + 64) * 64 + (m - 64)]);
      } else if (r < 12288) {
        // w2t: A-frags of W2^T, [mt 0..3][kk 0..1]
        const int s = r - 8192;
        const int j = s & 7, l = (s >> 3) & 15, q = (s >> 7) & 3;
        const int f = s >> 9, kk = f & 1, mt = f >> 1;
        const int k = kk * 32 + q * 8 + j;
        w2t[s] = (unsigned short)f2bf(W2[k * 64 + mt * 16 + l]);
      } else if (r < 20480) {
        // wu1t: A-frags of Wu1^T, [mt 0..3][kk 0..3]
        const int s = r - 12288;
        const int j = s & 7, l = (s >> 3) & 15, q = (s >> 7) & 3;
        const int f = s >> 9, kk = f & 3, mt = f >> 2;
        const int k = kk * 32 + q * 8 + j;        // 0..127
        wu1t[s] = (unsigned short)f2bf(Wu1[k * 64 + mt * 16 + l]);
      } else {
        // wu2b: B-frags of Wu2, [nt 0..3][kk 0..1]
        const int s = r - 20480;
        const int j = s & 7, l = (s >> 3) & 15, q = (s >> 7) & 3;
        const int f = s >> 9, kk = f & 1, nt = f >> 1;
        const int k = kk * 32 + q * 8 + j;
        wu2b[s] = (unsigned short)f2bf(Wu2[k * 64 + nt * 16 + l]);
      }
    } else if (t < 224576) {
      const int i = t - 174576;
      const float4* pp = (const float4*)(pos + 12 * i);   // 48B rows
      const float4 a = pp[0], b = pp[1], c = pp[2];
      float4 o;
      o.x = (a.x + a.w + b.z + c.y) * 0.25f;
      o.y = (a.y + b.x + b.w + c.z) * 0.25f;
      o.z = (a.z + b.y + c.x + c.w) * 0.25f;
      o.w = 0.f;
      ((float4*)cent4)[i] = o;
    }
  }
}

// ------------------------------------------------------------ msg_tail ----
// One block per 16-cell tile (3125 blocks, 4 waves).
__global__ __launch_bounds__(256) void msg_tail_kernel(
    const unsigned char* __restrict__ Q8,
    const float4* __restrict__ cent4,
    const int* __restrict__ nbr,
    const float* __restrict__ feat,
    const unsigned short* __restrict__ w1pq,
    const unsigned short* __restrict__ w2t,
    const unsigned short* __restrict__ wu1t,
    const unsigned short* __restrict__ wu2b,
    const float* __restrict__ b1, const float* __restrict__ W1,
    const float* __restrict__ b2, const float* __restrict__ bu1,
    const float* __restrict__ bu2,
    float* __restrict__ outf)
{
  __shared__ uint4 smem[432];   // sT (P then s) 16x144B | Msg 16x144B | Hb 16x144B
  char* sT  = (char*)smem;
  char* Msg = sT + 2304;
  char* Hb  = sT + 4608;

  const int lane = threadIdx.x & 63;
  const int wid  = threadIdx.x >> 6;
  const int quad = lane >> 4;
  const int l15  = lane & 15;
  const int tile = blockIdx.x;
  const int cr   = tile * 16 + l15;

  // ---- early independent loads: biases, neighbor rows, centroid gathers ----
  const float b1l = b1[lane];
  const float wl  = W1[8192 + lane];

  int nj[4];
  #pragma unroll
  for (int i = 0; i < 4; ++i) {
    const int cs = __builtin_amdgcn_readfirstlane(tile * 16 + wid * 4 + i);
    nj[i] = nbr[cs * DEG + l15];
  }
  float g[4];
  #pragma unroll
  for (int i = 0; i < 4; ++i) {
    const int cs = __builtin_amdgcn_readfirstlane(tile * 16 + wid * 4 + i);
    const float4 ci = cent4[cs];           // uniform -> s_load
    const float4 cj = cent4[nj[i]];        // random 16B gather
    const float dx = ci.x - cj.x, dy = ci.y - cj.y, dz = ci.z - cj.z;
    g[i] = sqrtf(dx * dx + dy * dy + dz * dz);
  }

  // ---- feat row -> bf16 frags, kept in regs for phase 0 AND stage 2 ----
  Frag xf[2];
  #pragma unroll
  for (int kk = 0; kk < 2; ++kk) {
    const float4 f0 = *(const float4*)(feat + cr * 64 + kk * 32 + quad * 8);
    const float4 f1 = *(const float4*)(feat + cr * 64 + kk * 32 + quad * 8 + 4);
    Frag v;
    v.s[0] = (short)f2bf(f0.x); v.s[1] = (short)f2bf(f0.y);
    v.s[2] = (short)f2bf(f0.z); v.s[3] = (short)f2bf(f0.w);
    v.s[4] = (short)f2bf(f1.x); v.s[5] = (short)f2bf(f1.y);
    v.s[6] = (short)f2bf(f1.z); v.s[7] = (short)f2bf(f1.w);
    xf[kk] = v;
  }

  // ---- phase 0: P-tile^T = W1top^T x X^T (mt = wid) -> LDS bf16 ----
  {
    short8 wpf[2];
    #pragma unroll
    for (int kk = 0; kk < 2; ++kk)
      wpf[kk] = *(const short8*)(w1pq + (((wid * 2 + kk) * 4 + quad) << 7) + l15 * 8);
    f32x4 accp = {};
    #pragma unroll
    for (int kk = 0; kk < 2; ++kk)
      accp = __builtin_amdgcn_mfma_f32_16x16x32_bf16(wpf[kk], xf[kk].s, accp, 0, 0, 0);
    uint2 pk;
    pk.x = f2bf(accp[0]) | (f2bf(accp[1]) << 16);
    pk.y = f2bf(accp[2]) | (f2bf(accp[3]) << 16);
    *(uint2_a*)(sT + l15 * 144 + wid * 32 + quad * 8) = pk;
  }

  // ---- prefetch cell 0's Q rows pre-barrier (latency hides in drain) ----
  unsigned qA[16], qB[16];
  #pragma unroll
  for (int d = 0; d < 16; ++d) {
    const int nd = __builtin_amdgcn_readlane(nj[0], d);
    qA[d] = Q8[nd * 64 + lane];
  }

  __syncthreads();

  // ---- phase A: 4 cells per wave, double-buffered Q8 prefetch ----
  #pragma unroll
  for (int i = 0; i < 4; ++i) {
    unsigned (&qc)[16] = (i & 1) ? qB : qA;
    unsigned (&qn)[16] = (i & 1) ? qA : qB;
    if (i < 3) {
      #pragma unroll
      for (int d = 0; d < 16; ++d) {
        const int nd = __builtin_amdgcn_readlane(nj[i + 1], d);
        qn[d] = Q8[nd * 64 + lane];
      }
    }
    const float pcb =
        bf2f(((const ushort_a*)(sT + (wid * 4 + i) * 144))[lane]) + b1l;
    float acc = 0.f;
    #pragma unroll
    for (int d = 0; d < 16; ++d) {
      const float gd = __uint_as_float(
          __builtin_amdgcn_readlane((int)__float_as_uint(g[i]), d));
      const float qv = __builtin_amdgcn_cvt_f32_fp8((int)qc[d], 0);
      acc += silu_fast(pcb + qv + gd * wl);
    }
    // overwrite own P row with s (only this wave reads this row's P)
    ((ushort_a*)(sT + (wid * 4 + i) * 144))[lane] =
        (unsigned short)f2bf(acc * 0.0625f);
  }

  // wave w's weight frags (mt/nt = wid only)
  short8 w2f[2], wu1f[4], wu2f[2];
  #pragma unroll
  for (int kk = 0; kk < 2; ++kk)
    w2f[kk]  = *(const short8*)(w2t  + (((wid * 2 + kk) * 4 + quad) << 7) + l15 * 8);
  #pragma unroll
  for (int kk = 0; kk < 4; ++kk)
    wu1f[kk] = *(const short8*)(wu1t + (((wid * 4 + kk) * 4 + quad) << 7) + l15 * 8);
  #pragma unroll
  for (int kk = 0; kk < 2; ++kk)
    wu2f[kk] = *(const short8*)(wu2b + (((wid * 2 + kk) * 4 + quad) << 7) + l15 * 8);

  const f32x4 b2f  = *(const f32x4*)(b2  + wid * 16 + quad * 4);
  const f32x4 bu1f = *(const f32x4*)(bu1 + wid * 16 + quad * 4);
  const float bu2v = bu2[wid * 16 + l15];

  __syncthreads();

  // ---- stage 1: msg^T = W2^T x s^T (+b2), mt = wid ----
  f32x4 accm = {};
  #pragma unroll
  for (int kk = 0; kk < 2; ++kk) {
    HbRd t; t.u = *(const uint4_a*)(sT + l15 * 144 + kk * 64 + quad * 16);
    accm = __builtin_amdgcn_mfma_f32_16x16x32_bf16(w2f[kk], t.s, accm, 0, 0, 0);
  }
  {
    uint2 pk;
    pk.x = f2bf(accm[0] + b2f[0]) | (f2bf(accm[1] + b2f[1]) << 16);
    pk.y = f2bf(accm[2] + b2f[2]) | (f2bf(accm[3] + b2f[3]) << 16);
    *(uint2_a*)(Msg + l15 * 144 + wid * 32 + quad * 8) = pk;
  }
  __syncthreads();

  // ---- stage 2: hu^T = Wu1^T x [feat|msg]^T (+bu1, silu), mt = wid ----
  f32x4 accu = {};
  #pragma unroll
  for (int kk = 0; kk < 4; ++kk) {
    short8 bf;
    if (kk < 2) {
      bf = xf[kk].s;
    } else {
      HbRd t; t.u = *(const uint4_a*)(Msg + l15 * 144 + (kk - 2) * 64 + quad * 16);
      bf = t.s;
    }
    accu = __builtin_amdgcn_mfma_f32_16x16x32_bf16(wu1f[kk], bf, accu, 0, 0, 0);
  }
  {
    float sv[4];
    #pragma unroll
    for (int rg = 0; rg < 4; ++rg)
      sv[rg] = silu(accu[rg] + bu1f[rg]);
    uint2 pk;
    pk.x = f2bf(sv[0]) | (f2bf(sv[1]) << 16);
    pk.y = f2bf(sv[2]) | (f2bf(sv[3]) << 16);
    *(uint2_a*)(Hb + l15 * 144 + wid * 32 + quad * 8) = pk;
  }
  __syncthreads();

  // ---- stage 3: out = hu x Wu2 + bu2 + feat, nt = wid ----
  f32x4 acc2 = {};
  #pragma unroll
  for (int kk = 0; kk < 2; ++kk) {
    HbRd t; t.u = *(const uint4_a*)(Hb + l15 * 144 + kk * 64 + quad * 16);
    acc2 = __builtin_amdgcn_mfma_f32_16x16x32_bf16(t.s, wu2f[kk], acc2, 0, 0, 0);
  }
  #pragma unroll
  for (int rg = 0; rg < 4; ++rg) {
    const int row = tile * 16 + quad * 4 + rg;
    const int col = wid * 16 + l15;
    outf[row * 64 + col] = feat[row * 64 + col] + acc2[rg] + bu2v;
  }
}

// -------------------------------------------------------------- launch ----
extern "C" void kernel_launch(void* const* d_in, const int* in_sizes, int n_in,
                              void* d_out, int out_size, void* d_ws, size_t ws_size,
                              hipStream_t stream)
{
  const float* feat = (const float*)d_in[0];
  const float* pos  = (const float*)d_in[1];
  const int*   nbr  = (const int*)d_in[2];
  const float* W1   = (const float*)d_in[3];
  const float* b1   = (const float*)d_in[4];
  const float* W2   = (const float*)d_in[5];
  const float* b2   = (const float*)d_in[6];
  const float* Wu1  = (const float*)d_in[7];
  const float* bu1  = (const float*)d_in[8];
  const float* Wu2  = (const float*)d_in[9];
  const float* bu2  = (const float*)d_in[10];
  float* out = (float*)d_out;

  // ws: Q8 fp8 3.2M @12.8M | cent4 0.8M @25.6M | swizzled weights @26.4M
  unsigned char*  Q8    = (unsigned char*)((char*)d_ws + 12800000);
  float*          cent4 = (float*)((char*)d_ws + 25600000);
  unsigned short* w1pq  = (unsigned short*)((char*)d_ws + 26400000);
  unsigned short* w2t   = (unsigned short*)((char*)d_ws + 26416384);
  unsigned short* wu1t  = (unsigned short*)((char*)d_ws + 26424576);
  unsigned short* wu2b  = (unsigned short*)((char*)d_ws + 26440960);

  prep_aux_kernel<<<1660, 256, 0, stream>>>(feat, pos, W1, W2, Wu1, Wu2,
                                            out + 3200000, cent4,
                                            w1pq, w2t, wu1t, wu2b, Q8);
  msg_tail_kernel<<<3125, 256, 0, stream>>>(Q8, (const float4*)cent4, nbr, feat,
                                            w1pq, w2t, wu1t, wu2b,
                                            b1, W1, b2, bu1, bu2, out);
}